// Round 5
// baseline (448.019 us; speedup 1.0000x reference)
//
#include <hip/hip_runtime.h>

// ---------------------------------------------------------------------------
// Attention (B=8, S=2048, H=1024, fp32 in/out), all-f16 MFMA pipeline.
// Round 4 (retry; R4 bench was lost to GPU-broker timeout):
//   ring-buffer GEMM + intra-wave software pipeline:
//   - 4-slot LDS ring, BK=32, prefetch distance 3, counted vmcnt(2*LPT)
//     (slots kt AND kt+1 resident at iter kt's top barrier),
//   - double fragment sets: issue slot kt+1's ds_reads BEFORE slot kt's MFMA,
//     so LDS reads overlap the MFMA phase within each wave,
//   - raw s_barrier, s_setprio(1) around the MFMA cluster.
// All GEMMs are C = A @ B^T with A[M][K] (row stride lda), Bt[N][K] (ldb).
// ---------------------------------------------------------------------------

typedef __attribute__((ext_vector_type(8))) _Float16 f16x8;
typedef __attribute__((ext_vector_type(4))) _Float16 f16x4;
typedef __attribute__((ext_vector_type(4))) float    f32x4;

constexpr int  B_ = 8, S_ = 2048, H_ = 1024;
constexpr long SH = (long)S_ * H_;   // per-batch q/k/v/x elements
constexpr long SS = (long)S_ * S_;   // per-batch score elements

#define DEVINL __device__ __forceinline__
template<int N> struct ic { static constexpr int v = N; };

#define EPI_QKV    0  // fused projection: q/k straight, v transposed, relu+bias
#define EPI_SCORES 2  // f32 out[row][ldc] = acc              (per-z batch)
#define EPI_PV     3  // f32 out[row][ldc] = acc + resid[idx] (per-z batch)

// ---- async global->LDS, 16B per lane; LDS dest is wave-uniform base ----
DEVINL void stage_as(void* dst, const void* src) {
  __builtin_amdgcn_global_load_lds(
      (const __attribute__((address_space(1))) unsigned int*)src,
      (__attribute__((address_space(3))) unsigned int*)dst, 16, 0, 0);
}

// Stage a [ROWS][32] f16 tile with 512 threads. LDS linear [row][32]; the 16B
// slot at LDS pos s holds global k-group s^((row>>1)&3) (swizzle applied on the
// GLOBAL source; global_load_lds writes lane i -> +16B*i).  Verified 2-way
// (free) bank conflicts on the paired frag() read (R1/R2 counters: 0 conflicts).
template<int ROWS>
DEVINL void stage_mat(_Float16* ldsb, const _Float16* g, int ldk, int tid) {
#pragma unroll
  for (int h = 0; h < ROWS / 128; ++h) {
    int t   = tid + h * 512;            // virtual thread, 4 x 16B slots per row
    int row = t >> 2;
    int gs  = (t & 3) ^ ((row >> 1) & 3);
    stage_as(ldsb + h * 4096 + ((tid >> 6) << 9),   // wave-uniform base (elems)
             g + (long)row * ldk + gs * 8);
  }
}

// Read one 16x32 MFMA fragment: lane holds 8 contiguous k at row (lane&15),
// k-group (lane>>4), stored XOR-swizzled.  2-way bank conflict only.
DEVINL f16x8 frag(const _Float16* lds, int row, int lane) {
  int r   = row + (lane & 15);
  int off = r * 32 + (((lane >> 4) ^ ((r >> 1) & 3)) << 3);
  return *(const f16x8*)(lds + off);
}

template<int EPI, int BM, int BN>
__global__ __launch_bounds__(512, 1)
void gemm_p(const _Float16* __restrict__ A, const _Float16* __restrict__ Bt,
            int K, int lda, int ldb, long aZ, long bZ, long cZ,
            const float* __restrict__ bs0, const float* __restrict__ bs1,
            const float* __restrict__ bs2, const float* __restrict__ resid,
            void* __restrict__ o0, void* __restrict__ o1, void* __restrict__ o2,
            int ldc)
{
  constexpr int WTM  = BM / 2;               // 8 waves as 2 (M) x 4 (N)
  constexpr int WTN  = BN / 4;
  constexpr int MI   = WTM / 16;
  constexpr int NI   = WTN / 16;
  constexpr int ASLOT = BM * 32;             // f16 elems per ring slot
  constexpr int SLOT  = (BM + BN) * 32;
  constexpr int LPT   = (BM + BN) / 128;     // global_load_lds per wave/slot

  __shared__ alignas(16) _Float16 lds[4 * SLOT];   // 4-slot ring

  const int tid  = threadIdx.x;
  const int wid  = tid >> 6;
  const int lane = tid & 63;
  const int wm   = wid >> 2, wn = wid & 3;
  const int z    = blockIdx.z;

  const _Float16* a0 = A  + (long)z * aZ + (long)blockIdx.x * BM * lda;
  const _Float16* b0 = Bt + (long)z * bZ + (long)blockIdx.y * BN * ldb;

  f32x4 acc[MI][NI];
#pragma unroll
  for (int mi = 0; mi < MI; ++mi)
#pragma unroll
    for (int ni = 0; ni < NI; ++ni)
      acc[mi][ni] = (f32x4){0.f, 0.f, 0.f, 0.f};

  const int NT = K >> 5;                     // K-tiles of 32 (NT even, >= 8)

  auto stage = [&](int t) {                  // slot t -> ring[t&3]
    _Float16* s = lds + (size_t)(t & 3) * SLOT;
    stage_mat<BM>(s,         a0 + t * 32, lda, tid);
    stage_mat<BN>(s + ASLOT, b0 + t * 32, ldb, tid);
  };

  auto loadFrags = [&](const _Float16* sA, const _Float16* sB,
                       f16x8 (&af)[MI], f16x8 (&bf)[NI]) {
#pragma unroll
    for (int mi = 0; mi < MI; ++mi) af[mi] = frag(sA, wm * WTM + mi * 16, lane);
#pragma unroll
    for (int ni = 0; ni < NI; ++ni) bf[ni] = frag(sB, wn * WTN + ni * 16, lane);
  };

  // Invariants:
  //  - ring[t&3] is overwritten only by stage(t+4), issued after the end-of-
  //    iter-t barrier; every wave's slot-t ds_reads complete before its MFMA
  //    (dependency waitcnt), hence before that barrier.  No overwrite race.
  //  - vmcnt(2*LPT) at iter t's top keeps only slots t+2,t+3 in flight, so
  //    slots t AND t+1 are LDS-resident after the top barrier; ds_reads for
  //    slot t+1 issue immediately and complete under slot t's MFMA cluster.
  auto body = [&](auto vm, int kt, bool dostage, bool doreads,
                  f16x8 (&afC)[MI], f16x8 (&bfC)[NI],
                  f16x8 (&afN)[MI], f16x8 (&bfN)[NI]) {
    if (dostage) stage(kt + 3);
    asm volatile("s_waitcnt vmcnt(%0)" :: "n"(decltype(vm)::v) : "memory");
    __builtin_amdgcn_s_barrier();
    asm volatile("" ::: "memory");
    if (doreads) {
      const _Float16* nA = lds + (size_t)((kt + 1) & 3) * SLOT;
      loadFrags(nA, nA + ASLOT, afN, bfN);
    }
    __builtin_amdgcn_s_setprio(1);
#pragma unroll
    for (int mi = 0; mi < MI; ++mi)
#pragma unroll
      for (int ni = 0; ni < NI; ++ni)
        acc[mi][ni] = __builtin_amdgcn_mfma_f32_16x16x32_f16(afC[mi], bfC[ni], acc[mi][ni], 0, 0, 0);
    __builtin_amdgcn_s_setprio(0);
    asm volatile("" ::: "memory");
    __builtin_amdgcn_s_barrier();            // frees ring[kt&3] for stage(kt+4)
  };

  // prologue: 3 slots in flight; drain slot 0; preload its fragments (set A)
  stage(0); stage(1); stage(2);
  asm volatile("s_waitcnt vmcnt(%0)" :: "n"(2 * LPT) : "memory");
  __builtin_amdgcn_s_barrier();
  asm volatile("" ::: "memory");
  f16x8 afA[MI], bfA[NI], afB[MI], bfB[NI];
  loadFrags(lds, lds + ASLOT, afA, bfA);

  int kt = 0;
  for (; kt < NT - 4; kt += 2) {             // slot kt in set A (kt even)
    body(ic<2 * LPT>{}, kt,     true,  true,  afA, bfA, afB, bfB);
    body(ic<2 * LPT>{}, kt + 1, true,  true,  afB, bfB, afA, bfA);
  }
  body(ic<2 * LPT>{}, kt, true,  true,  afA, bfA, afB, bfB); ++kt;  // NT-4
  body(ic<1 * LPT>{}, kt, false, true,  afB, bfB, afA, bfA); ++kt;  // NT-3
  body(ic<0>{},       kt, false, true,  afA, bfA, afB, bfB); ++kt;  // NT-2
  body(ic<0>{},       kt, false, false, afB, bfB, afA, bfA);        // NT-1

  // Epilogue. C/D layout: col = lane&15, row = 4*(lane>>4) + r  [verified]
  const int rb = blockIdx.x * BM + wm * WTM + ((lane >> 4) << 2);
  const int cb = blockIdx.y * BN + wn * WTN + (lane & 15);
#pragma unroll
  for (int mi = 0; mi < MI; ++mi) {
#pragma unroll
    for (int ni = 0; ni < NI; ++ni) {
      const int row0 = rb + mi * 16;
      const int col  = cb + ni * 16;
      if constexpr (EPI == EPI_QKV) {
        // col in [0,3072): section 0->q, 1->k, 2->v(transposed)
        const int sect = col >> 10;
        const int c    = col & 1023;
        const float* bias = (sect == 0) ? bs0 : (sect == 1) ? bs1 : bs2;
        const float bv = bias[c];
        if (sect < 2) {
          _Float16* o = (_Float16*)(sect == 0 ? o0 : o1);
#pragma unroll
          for (int r = 0; r < 4; ++r)
            o[(long)(row0 + r) * 1024 + c] = (_Float16)fmaxf(acc[mi][ni][r] + bv, 0.f);
        } else {
          _Float16* o = (_Float16*)o2;        // vt[(b*1024+c)*2048 + s]
          f16x4 pk;
#pragma unroll
          for (int r = 0; r < 4; ++r)
            pk[r] = (_Float16)fmaxf(acc[mi][ni][r] + bv, 0.f);
          const long b = row0 >> 11;          // batch (S=2048 rows per batch)
          const long s = row0 & 2047;         // multiple of 4 -> aligned f16x4
          *(f16x4*)(o + ((b << 10) + c) * 2048 + s) = pk;
        }
      } else if constexpr (EPI == EPI_SCORES) {
        float* o = (float*)o0 + (long)z * cZ;
#pragma unroll
        for (int r = 0; r < 4; ++r)
          o[(long)(row0 + r) * ldc + col] = acc[mi][ni][r];
      } else {  // EPI_PV
        float* o = (float*)o0 + (long)z * cZ;
        const float* rs = resid + (long)z * cZ;
#pragma unroll
        for (int r = 0; r < 4; ++r) {
          const long idx = (long)(row0 + r) * ldc + col;
          o[idx] = acc[mi][ni][r] + rs[idx];
        }
      }
    }
  }
}

// ---- row softmax, IN PLACE: reads f32 row, writes f16 P into the row start.
__global__ __launch_bounds__(256)
void softmax_k(float* __restrict__ Sc, const float* __restrict__ mask)
{
  const int z    = blockIdx.y;
  float*       s  = Sc + (long)z * SS;
  const float* mk = mask + (long)z * S_;
  const int row  = blockIdx.x * 4 + (threadIdx.x >> 6);
  const int lane = threadIdx.x & 63;

  const float4* sr = (const float4*)(s + (long)row * S_);
  const float4* mr = (const float4*)mk;
  float4 v[8];
  float  mx = -3.0e38f;
#pragma unroll
  for (int c = 0; c < 8; ++c) {
    float4 sv = sr[c * 64 + lane];
    float4 mv = mr[c * 64 + lane];
    sv.x -= 1e10f * (1.f - mv.x);
    sv.y -= 1e10f * (1.f - mv.y);
    sv.z -= 1e10f * (1.f - mv.z);
    sv.w -= 1e10f * (1.f - mv.w);
    v[c] = sv;
    mx = fmaxf(mx, fmaxf(fmaxf(sv.x, sv.y), fmaxf(sv.z, sv.w)));
  }
#pragma unroll
  for (int d = 32; d; d >>= 1) mx = fmaxf(mx, __shfl_xor(mx, d));
  float sum = 0.f;
#pragma unroll
  for (int c = 0; c < 8; ++c) {
    v[c].x = __expf(v[c].x - mx);
    v[c].y = __expf(v[c].y - mx);
    v[c].z = __expf(v[c].z - mx);
    v[c].w = __expf(v[c].w - mx);
    sum += (v[c].x + v[c].y) + (v[c].z + v[c].w);
  }
#pragma unroll
  for (int d = 32; d; d >>= 1) sum += __shfl_xor(sum, d);
  const float inv = 1.f / sum;
  f16x4* pr = (f16x4*)(s + (long)row * S_);   // in-place: f16 row over f32 row
#pragma unroll
  for (int c = 0; c < 8; ++c) {
    f16x4 o = {(_Float16)(v[c].x * inv), (_Float16)(v[c].y * inv),
               (_Float16)(v[c].z * inv), (_Float16)(v[c].w * inv)};
    pr[c * 64 + lane] = o;
  }
}

// ---- fp32 -> f16 conversion, float4 per thread ----
__global__ __launch_bounds__(256)
void cvt_f16(const float* __restrict__ x, _Float16* __restrict__ y, int n4)
{
  const int i = blockIdx.x * 256 + threadIdx.x;
  if (i >= n4) return;
  const float4 v = ((const float4*)x)[i];
  f16x4 o = {(_Float16)v.x, (_Float16)v.y, (_Float16)v.z, (_Float16)v.w};
  ((f16x4*)y)[i] = o;
}

// three weight matrices -> one contiguous [3072][1024] f16 matrix
__global__ __launch_bounds__(256)
void cvt_w3(const float* __restrict__ a, const float* __restrict__ b,
            const float* __restrict__ c, _Float16* __restrict__ y)
{
  const int i = blockIdx.x * 256 + threadIdx.x;       // n4 = 1024*1024/4
  const float* src = (blockIdx.y == 0) ? a : (blockIdx.y == 1) ? b : c;
  const float4 v = ((const float4*)src)[i];
  f16x4 o = {(_Float16)v.x, (_Float16)v.y, (_Float16)v.z, (_Float16)v.w};
  ((f16x4*)(y + (long)blockIdx.y * H_ * H_))[i] = o;
}

extern "C" void kernel_launch(void* const* d_in, const int* in_sizes, int n_in,
                              void* d_out, int out_size, void* d_ws, size_t ws_size,
                              hipStream_t stream)
{
  const float* input = (const float*)d_in[0];  // [8,2048,1024]
  const float* mask  = (const float*)d_in[1];  // [8,1,2048]
  const float* Wq    = (const float*)d_in[2];
  const float* bq    = (const float*)d_in[3];
  const float* Wk    = (const float*)d_in[4];
  const float* bk    = (const float*)d_in[5];
  const float* Wv    = (const float*)d_in[6];
  const float* bv    = (const float*)d_in[7];
  float* out = (float*)d_out;

  // workspace carve (peak 160 MB; xh/wAll dead before sc is written)
  char* w = (char*)d_ws;
  _Float16* q    = (_Float16*)(w);                     // 32 MB [0,32)
  _Float16* k    = (_Float16*)(w + (32l << 20));       // 32 MB [32,64)
  _Float16* vt   = (_Float16*)(w + (64l << 20));       // 32 MB [64,96)  [b][d][s]
  _Float16* xh   = (_Float16*)(w + (96l << 20));       // 32 MB [96,128) (dead after proj)
  _Float16* wAll = (_Float16*)(w + (128l << 20));      //  6 MB [128,134) (dead after proj)
  float*    sc   = (float*)   (w + (96l << 20));       // 64 MB [96,160) (4 batches f32)

  // 1) fp32 -> f16 conversions
  cvt_f16<<<16384, 256, 0, stream>>>(input, xh, (int)(B_ * SH / 4));
  cvt_w3<<<dim3(1024, 3), 256, 0, stream>>>(Wq, Wk, Wv, wAll);

  // 2) fused QKV projection: [16384,3072] = x @ [Wq;Wk;Wv]^T (+bias, relu)
  gemm_p<EPI_QKV, 256, 256><<<dim3(64, 12, 1), 512, 0, stream>>>(
      xh, wAll, H_, H_, H_, 0, 0, 0, bq, bk, bv, nullptr, q, k, vt, 0);

  // 3) attention, 4 batches per round (z dim), scores/P scratch reused
  for (int r = 0; r < 2; ++r) {
    const long b0 = (long)r * 4;
    gemm_p<EPI_SCORES, 256, 256><<<dim3(8, 8, 4), 512, 0, stream>>>(
        q + b0 * SH, k + b0 * SH, H_, H_, H_, SH, SH, SS,
        nullptr, nullptr, nullptr, nullptr, sc, nullptr, nullptr, S_);
    softmax_k<<<dim3(512, 4), 256, 0, stream>>>(sc, mask + b0 * S_);
    gemm_p<EPI_PV, 256, 128><<<dim3(8, 8, 4), 512, 0, stream>>>(
        (const _Float16*)sc, vt + b0 * SH, S_, 2 * S_, S_, 2 * SS, SH, SH,
        nullptr, nullptr, nullptr, input + b0 * SH, out + b0 * SH, nullptr, nullptr, H_);
  }
}

// Round 6
// 435.502 us; speedup vs baseline: 1.0287x; 1.0287x over previous
//
#include <hip/hip_runtime.h>

// ---------------------------------------------------------------------------
// Attention (B=8, S=2048, H=1024, fp32 in/out), all-f16 MFMA pipeline.
// Round 6: fine-grained 4-phase GEMM schedule (m201-style, re-derived):
//  - BM=256, BK=64 K-tiles, 2-slot LDS double buffer,
//  - tile split into 4 phases = C-quadrants, 16 MFMA each, with per-phase
//    {vmcnt? -> barrier -> ds_read subtile -> stage 1 half-tile -> barrier
//     -> setprio(1) MFMA setprio(0)},
//  - minimal LDS reads (A once/half, B frags held in regs across phases),
//  - stage halves = LDS-death regions; prefetch distance 2 tiles; counted
//    vmcnt only at phases 0/1 (never 0 until the peeled last tile).
// All GEMMs are C = A @ B^T with A[M][K] (row stride lda), Bt[N][K] (ldb).
// ---------------------------------------------------------------------------

typedef __attribute__((ext_vector_type(8))) _Float16 f16x8;
typedef __attribute__((ext_vector_type(4))) _Float16 f16x4;
typedef __attribute__((ext_vector_type(4))) float    f32x4;

constexpr int  B_ = 8, S_ = 2048, H_ = 1024;
constexpr long SH = (long)S_ * H_;   // per-batch q/k/v/x elements
constexpr long SS = (long)S_ * S_;   // per-batch score elements

#define DEVINL __device__ __forceinline__

#define EPI_QKV    0  // fused projection: q/k straight, v transposed, relu+bias
#define EPI_SCORES 2  // f32 out[row][ldc] = acc              (per-z batch)
#define EPI_PV     3  // f32 out[row][ldc] = acc + resid[idx] (per-z batch)

// ---- async global->LDS, 16B per lane; LDS dest is wave-uniform base ----
DEVINL void stage_as(void* dst, const void* src) {
  __builtin_amdgcn_global_load_lds(
      (const __attribute__((address_space(1))) unsigned int*)src,
      (__attribute__((address_space(3))) unsigned int*)dst, 16, 0, 0);
}

#define FBAR() do { asm volatile("" ::: "memory");                    \
                    __builtin_amdgcn_s_barrier();                     \
                    asm volatile("" ::: "memory"); } while (0)
#define VMW(N) asm volatile("s_waitcnt vmcnt(%0)" :: "n"(N) : "memory")

// Read A fragments for row-half QR: 4 row-tiles x 2 ksteps (8 x ds_read_b128).
// LDS rows are 64 f16 (8 x 16B slots); slot s holds global k-group s^(row&7)
// (swizzle applied on the GLOBAL source at stage time; reads conflict-free:
// 16 consecutive rows -> 8 slot positions x 2 lanes = minimal 2-way).
#define READ_A(T, QR, AF)                                                    \
  {                                                                          \
    const _Float16* _ba = lds + ((T) & 1) * BUFSZ + (QR) * AHALF             \
                          + (wm * 64) * 64;                                  \
    _Pragma("unroll")                                                        \
    for (int miq = 0; miq < 4; ++miq) {                                      \
      const int rr = (lane & 15) + miq * 16;                                 \
      _Pragma("unroll")                                                      \
      for (int kk = 0; kk < 2; ++kk) {                                       \
        const int sl = (kk * 4 + (lane >> 4)) ^ (rr & 7);                    \
        AF[miq][kk] = *(const f16x8*)(_ba + rr * 64 + sl * 8);               \
      }                                                                      \
    }                                                                        \
  }

#define READ_B(T, QC, BF)                                                    \
  {                                                                          \
    const _Float16* _bb = lds + ((T) & 1) * BUFSZ + 2 * AHALF                \
                          + (QC) * BHALF + (wn * SB) * 64;                   \
    _Pragma("unroll")                                                        \
    for (int niq = 0; niq < NIQ; ++niq) {                                    \
      const int cc = (lane & 15) + niq * 16;                                 \
      _Pragma("unroll")                                                      \
      for (int kk = 0; kk < 2; ++kk) {                                       \
        const int sl = (kk * 4 + (lane >> 4)) ^ (cc & 7);                    \
        BF[niq][kk] = *(const f16x8*)(_bb + cc * 64 + sl * 8);               \
      }                                                                      \
    }                                                                        \
  }

#define MMAQ(QR, QC, AF, BF)                                                 \
  {                                                                          \
    __builtin_amdgcn_s_setprio(1);                                           \
    _Pragma("unroll")                                                        \
    for (int kk = 0; kk < 2; ++kk)                                           \
      _Pragma("unroll")                                                      \
      for (int miq = 0; miq < 4; ++miq)                                      \
        _Pragma("unroll")                                                    \
        for (int niq = 0; niq < NIQ; ++niq)                                  \
          acc[(QR) * 4 + miq][(QC) * NIQ + niq] =                            \
              __builtin_amdgcn_mfma_f32_16x16x32_f16(                        \
                  AF[miq][kk], BF[niq][kk],                                  \
                  acc[(QR) * 4 + miq][(QC) * NIQ + niq], 0, 0, 0);           \
    __builtin_amdgcn_s_setprio(0);                                           \
  }

// One K-tile = 4 phases.  Stage schedule (into buf[s&1], regions dead one
// phase earlier): p1: B_qc0(s+2), p2: A_lo(s+2), p3: B_qc1(s+2)+A_hi(s+2).
#define TILE(S, VM0N, VM1N, DOST)                                            \
  {                                                                          \
    f16x8 afq[4][2], bf0[NIQ][2], bf1[NIQ][2];                               \
    VMW(VM0N); FBAR();                       /* phase 0: (qr0,qc0) */        \
    READ_A(S, 0, afq); READ_B(S, 0, bf0);                                    \
    FBAR();                                                                  \
    MMAQ(0, 0, afq, bf0);                                                    \
    VMW(VM1N); FBAR();                       /* phase 1: (qr0,qc1) */        \
    READ_B(S, 1, bf1);                                                       \
    if (DOST) stageB((S) + 2, 0);                                            \
    FBAR();                                                                  \
    MMAQ(0, 1, afq, bf1);                                                    \
    FBAR();                                  /* phase 2: (qr1,qc1) */        \
    READ_A(S, 1, afq);                                                       \
    if (DOST) stageA((S) + 2, 0);                                            \
    FBAR();                                                                  \
    MMAQ(1, 1, afq, bf1);                                                    \
    FBAR();                                  /* phase 3: (qr1,qc0) */        \
    if (DOST) { stageB((S) + 2, 1); stageA((S) + 2, 1); }                    \
    FBAR();                                                                  \
    MMAQ(1, 0, afq, bf0);                                                    \
  }

template<int EPI, int BN>
__global__ __launch_bounds__(512, 1)
void gemm8(const _Float16* __restrict__ A, const _Float16* __restrict__ Bt,
           int K, int lda, int ldb, long aZ, long bZ, long cZ,
           const float* __restrict__ bs0, const float* __restrict__ bs1,
           const float* __restrict__ bs2, const float* __restrict__ resid,
           void* __restrict__ o0, void* __restrict__ o1, void* __restrict__ o2,
           int ldc)
{
  constexpr int BM   = 256;
  constexpr int WTN  = BN / 4;         // 8 waves as 2 (M) x 4 (N)
  constexpr int NI   = BN / 64;        // 16-col tiles per wave
  constexpr int NIQ  = BN / 128;       // 16-col tiles per quadrant-phase
  constexpr int SB   = BN / 8;         // B stripe rows per wn per half
  constexpr int LA   = 2;              // gload_lds/thread per A-half
  constexpr int LB   = BN / 128;       // gload_lds/thread per B-half
  constexpr int AHALF = 128 * 64;      // f16 per A half  (rows: {lo},{hi})
  constexpr int BHALF = (BN / 2) * 64; // f16 per B half  (qc0/qc1 stripes)
  constexpr int BUFSZ = 2 * AHALF + 2 * BHALF;

  __shared__ alignas(16) _Float16 lds[2 * BUFSZ];  // 128 KB (BN=256) / 96 KB

  const int tid  = threadIdx.x;
  const int wid  = tid >> 6;
  const int lane = tid & 63;
  const int wm   = wid >> 2, wn = wid & 3;
  const int z    = blockIdx.z;

  const _Float16* a0 = A  + (long)z * aZ + (long)blockIdx.x * BM * lda;
  const _Float16* b0 = Bt + (long)z * bZ + (long)blockIdx.y * BN * ldb;

  f32x4 acc[8][NI];
#pragma unroll
  for (int mi = 0; mi < 8; ++mi)
#pragma unroll
    for (int ni = 0; ni < NI; ++ni)
      acc[mi][ni] = (f32x4){0.f, 0.f, 0.f, 0.f};

  const int NT = K >> 6;               // K-tiles of 64 (NT >= 2)

  // A half h = global rows {h*64 + (i&63) + (i>>6)*128}: LDS row i linear.
  auto stageA = [&](int t, int h) {
    _Float16* base = lds + (t & 1) * BUFSZ + h * AHALF + ((tid >> 6) << 9);
#pragma unroll
    for (int j = 0; j < LA; ++j) {
      const int vt   = tid + j * 512;
      const int i    = vt >> 3;                       // LDS row in half
      const int p    = vt & 7;                        // 16B slot
      const int grow = h * 64 + (i & 63) + (i >> 6) * 128;
      const int gs   = p ^ (i & 7);                   // source k-group swizzle
      stage_as(base + j * 4096, a0 + (long)grow * lda + t * 64 + gs * 8);
    }
  };
  // B half h = global rows {(i/SB)*(2SB) + h*SB + i%SB}: stripes of SB.
  auto stageB = [&](int t, int h) {
    _Float16* base = lds + (t & 1) * BUFSZ + 2 * AHALF + h * BHALF
                     + ((tid >> 6) << 9);
#pragma unroll
    for (int j = 0; j < LB; ++j) {
      const int vt   = tid + j * 512;
      const int i    = vt >> 3;
      const int p    = vt & 7;
      const int grow = (i / SB) * (2 * SB) + h * SB + (i % SB);
      const int gs   = p ^ (i & 7);
      stage_as(base + j * 4096, b0 + (long)grow * ldb + t * 64 + gs * 8);
    }
  };

  // prologue: tiles 0 and 1 fully staged, order [B0,A0,B1,A1] per tile so
  // the steady vmcnt accounting holds from s=0.
  stageB(0, 0); stageA(0, 0); stageB(0, 1); stageA(0, 1);
  stageB(1, 0); stageA(1, 0); stageB(1, 1); stageA(1, 1);

  for (int s = 0; s < NT - 1; ++s) {
    const bool dost = (s + 2 < NT);
    TILE(s, 3 * (LA + LB), 2 * (LA + LB), dost);
  }
  TILE(NT - 1, LA + LB, 0, false);     // peeled last tile: drain

  // Epilogue. C/D layout: col = lane&15, row = 4*(lane>>4) + r  [verified]
  const int rb = blockIdx.x * BM + wm * 128 + ((lane >> 4) << 2);
  const int cb = blockIdx.y * BN + wn * WTN + (lane & 15);
#pragma unroll
  for (int mi = 0; mi < 8; ++mi) {
#pragma unroll
    for (int ni = 0; ni < NI; ++ni) {
      const int row0 = rb + mi * 16;
      const int col  = cb + ni * 16;
      if constexpr (EPI == EPI_QKV) {
        // col in [0,3072): section 0->q, 1->k, 2->v(transposed)
        const int sect = col >> 10;
        const int c    = col & 1023;
        const float* bias = (sect == 0) ? bs0 : (sect == 1) ? bs1 : bs2;
        const float bv = bias[c];
        if (sect < 2) {
          _Float16* o = (_Float16*)(sect == 0 ? o0 : o1);
#pragma unroll
          for (int r = 0; r < 4; ++r)
            o[(long)(row0 + r) * 1024 + c] = (_Float16)fmaxf(acc[mi][ni][r] + bv, 0.f);
        } else {
          _Float16* o = (_Float16*)o2;        // vt[(b*1024+c)*2048 + s]
          f16x4 pk;
#pragma unroll
          for (int r = 0; r < 4; ++r)
            pk[r] = (_Float16)fmaxf(acc[mi][ni][r] + bv, 0.f);
          const long b = row0 >> 11;          // batch (S=2048 rows per batch)
          const long s2 = row0 & 2047;        // multiple of 4 -> aligned f16x4
          *(f16x4*)(o + ((b << 10) + c) * 2048 + s2) = pk;
        }
      } else if constexpr (EPI == EPI_SCORES) {
        float* o = (float*)o0 + (long)z * cZ;
#pragma unroll
        for (int r = 0; r < 4; ++r)
          o[(long)(row0 + r) * ldc + col] = acc[mi][ni][r];
      } else {  // EPI_PV
        float* o = (float*)o0 + (long)z * cZ;
        const float* rs = resid + (long)z * cZ;
#pragma unroll
        for (int r = 0; r < 4; ++r) {
          const long idx = (long)(row0 + r) * ldc + col;
          o[idx] = acc[mi][ni][r] + rs[idx];
        }
      }
    }
  }
}

// ---- row softmax, IN PLACE: reads f32 row, writes f16 P into the row start.
__global__ __launch_bounds__(256)
void softmax_k(float* __restrict__ Sc, const float* __restrict__ mask)
{
  const int z    = blockIdx.y;
  float*       s  = Sc + (long)z * SS;
  const float* mk = mask + (long)z * S_;
  const int row  = blockIdx.x * 4 + (threadIdx.x >> 6);
  const int lane = threadIdx.x & 63;

  const float4* sr = (const float4*)(s + (long)row * S_);
  const float4* mr = (const float4*)mk;
  float4 v[8];
  float  mx = -3.0e38f;
#pragma unroll
  for (int c = 0; c < 8; ++c) {
    float4 sv = sr[c * 64 + lane];
    float4 mv = mr[c * 64 + lane];
    sv.x -= 1e10f * (1.f - mv.x);
    sv.y -= 1e10f * (1.f - mv.y);
    sv.z -= 1e10f * (1.f - mv.z);
    sv.w -= 1e10f * (1.f - mv.w);
    v[c] = sv;
    mx = fmaxf(mx, fmaxf(fmaxf(sv.x, sv.y), fmaxf(sv.z, sv.w)));
  }
#pragma unroll
  for (int d = 32; d; d >>= 1) mx = fmaxf(mx, __shfl_xor(mx, d));
  float sum = 0.f;
#pragma unroll
  for (int c = 0; c < 8; ++c) {
    v[c].x = __expf(v[c].x - mx);
    v[c].y = __expf(v[c].y - mx);
    v[c].z = __expf(v[c].z - mx);
    v[c].w = __expf(v[c].w - mx);
    sum += (v[c].x + v[c].y) + (v[c].z + v[c].w);
  }
#pragma unroll
  for (int d = 32; d; d >>= 1) sum += __shfl_xor(sum, d);
  const float inv = 1.f / sum;
  f16x4* pr = (f16x4*)(s + (long)row * S_);   // in-place: f16 row over f32 row
#pragma unroll
  for (int c = 0; c < 8; ++c) {
    f16x4 o = {(_Float16)(v[c].x * inv), (_Float16)(v[c].y * inv),
               (_Float16)(v[c].z * inv), (_Float16)(v[c].w * inv)};
    pr[c * 64 + lane] = o;
  }
}

// ---- fp32 -> f16 conversion, float4 per thread ----
__global__ __launch_bounds__(256)
void cvt_f16(const float* __restrict__ x, _Float16* __restrict__ y, int n4)
{
  const int i = blockIdx.x * 256 + threadIdx.x;
  if (i >= n4) return;
  const float4 v = ((const float4*)x)[i];
  f16x4 o = {(_Float16)v.x, (_Float16)v.y, (_Float16)v.z, (_Float16)v.w};
  ((f16x4*)y)[i] = o;
}

// three weight matrices -> one contiguous [3072][1024] f16 matrix
__global__ __launch_bounds__(256)
void cvt_w3(const float* __restrict__ a, const float* __restrict__ b,
            const float* __restrict__ c, _Float16* __restrict__ y)
{
  const int i = blockIdx.x * 256 + threadIdx.x;       // n4 = 1024*1024/4
  const float* src = (blockIdx.y == 0) ? a : (blockIdx.y == 1) ? b : c;
  const float4 v = ((const float4*)src)[i];
  f16x4 o = {(_Float16)v.x, (_Float16)v.y, (_Float16)v.z, (_Float16)v.w};
  ((f16x4*)(y + (long)blockIdx.y * H_ * H_))[i] = o;
}

extern "C" void kernel_launch(void* const* d_in, const int* in_sizes, int n_in,
                              void* d_out, int out_size, void* d_ws, size_t ws_size,
                              hipStream_t stream)
{
  const float* input = (const float*)d_in[0];  // [8,2048,1024]
  const float* mask  = (const float*)d_in[1];  // [8,1,2048]
  const float* Wq    = (const float*)d_in[2];
  const float* bq    = (const float*)d_in[3];
  const float* Wk    = (const float*)d_in[4];
  const float* bk    = (const float*)d_in[5];
  const float* Wv    = (const float*)d_in[6];
  const float* bv    = (const float*)d_in[7];
  float* out = (float*)d_out;

  // workspace carve (peak 160 MB; xh/wAll dead before sc is written)
  char* w = (char*)d_ws;
  _Float16* q    = (_Float16*)(w);                     // 32 MB [0,32)
  _Float16* k    = (_Float16*)(w + (32l << 20));       // 32 MB [32,64)
  _Float16* vt   = (_Float16*)(w + (64l << 20));       // 32 MB [64,96)  [b][d][s]
  _Float16* xh   = (_Float16*)(w + (96l << 20));       // 32 MB [96,128) (dead after proj)
  _Float16* wAll = (_Float16*)(w + (128l << 20));      //  6 MB [128,134) (dead after proj)
  float*    sc   = (float*)   (w + (96l << 20));       // 64 MB [96,160) (4 batches f32)

  // 1) fp32 -> f16 conversions
  cvt_f16<<<16384, 256, 0, stream>>>(input, xh, (int)(B_ * SH / 4));
  cvt_w3<<<dim3(1024, 3), 256, 0, stream>>>(Wq, Wk, Wv, wAll);

  // 2) fused QKV projection: [16384,3072] = x @ [Wq;Wk;Wv]^T (+bias, relu)
  gemm8<EPI_QKV, 256><<<dim3(64, 12, 1), 512, 0, stream>>>(
      xh, wAll, H_, H_, H_, 0, 0, 0, bq, bk, bv, nullptr, q, k, vt, 0);

  // 3) attention, 4 batches per round (z dim), scores/P scratch reused
  for (int r = 0; r < 2; ++r) {
    const long b0 = (long)r * 4;
    gemm8<EPI_SCORES, 256><<<dim3(8, 8, 4), 512, 0, stream>>>(
        q + b0 * SH, k + b0 * SH, H_, H_, H_, SH, SH, SS,
        nullptr, nullptr, nullptr, nullptr, sc, nullptr, nullptr, S_);
    softmax_k<<<dim3(512, 4), 256, 0, stream>>>(sc, mask + b0 * S_);
    gemm8<EPI_PV, 128><<<dim3(8, 8, 4), 512, 0, stream>>>(
        (const _Float16*)sc, vt + b0 * SH, S_, 2 * S_, S_, 2 * SS, SH, SH,
        nullptr, nullptr, nullptr, input + b0 * SH, out + b0 * SH, nullptr, nullptr, H_);
  }
}